// Round 8
// baseline (1679.908 us; speedup 1.0000x reference)
//
#include <hip/hip_runtime.h>

#define NPTS 524288
#define NSEG 64
#define WR 16                     // rows per wave
#define NWAVE (NPTS / WR)         // 32768 waves
#define MAXPW (NWAVE + NSEG)      // max part records

typedef __bf16 bf16x8 __attribute__((ext_vector_type(8)));
typedef float f32x4 __attribute__((ext_vector_type(4)));

__device__ __forceinline__ unsigned int f2bf(float f) {
  unsigned int u = __float_as_uint(f);
  return (u + 0x7FFFu + ((u >> 16) & 1u)) >> 16;  // RNE bf16
}

// Branchless erf, Abramowitz-Stegun 7.1.26, |err| <= 1.5e-7
__device__ __forceinline__ float gelu_f(float h) {
  const float u = 0.70710678118654752f * h;
  const float a = fabsf(u);
  const float t = __builtin_amdgcn_rcpf(fmaf(0.3275911f, a, 1.0f));
  const float e = __expf(-a * a);
  float p = fmaf(1.061405429f, t, -1.453152027f);
  p = fmaf(p, t, 1.421413741f);
  p = fmaf(p, t, -0.284496736f);
  p = fmaf(p, t, 0.254829592f);
  p *= t;
  const float erfa = fmaf(-p, e, 1.0f);
  const float erfu = copysignf(erfa, u);
  return 0.5f * h * (1.0f + erfu);
}

// ---------------- prep: w1 [512][256] f32 -> bf16 packed [(k>>3)][n][k&7] ----------------
__global__ void prep_w1(const float* __restrict__ w1, unsigned short* __restrict__ w1p) {
  const int n = threadIdx.x;         // 0..255
  const int k0 = blockIdx.x * 8;     // 0..504
  unsigned int d[4];
  #pragma unroll
  for (int j = 0; j < 4; ++j) {
    const unsigned int lo = f2bf(w1[(size_t)(k0 + 2 * j) * 256 + n]);
    const unsigned int hi = f2bf(w1[(size_t)(k0 + 2 * j + 1) * 256 + n]);
    d[j] = lo | (hi << 16);
  }
  uint4* dst = (uint4*)(w1p + (size_t)blockIdx.x * 2048 + n * 8);
  *dst = make_uint4(d[0], d[1], d[2], d[3]);
}

// ---------------- fused: per-wave 16 rows, register-resident, NO LDS, NO barriers ----------
// LN -> MFMA GEMM (M-split) -> GELU -> s -> per-(wave,seg) partial {m,z,P[512]}.
__global__ __launch_bounds__(256, 2) void fused_kernel(
    const float* __restrict__ feats, const float* __restrict__ ln_w,
    const float* __restrict__ ln_b, const unsigned short* __restrict__ w1p,
    const float* __restrict__ b1, const float* __restrict__ w2,
    const float* __restrict__ b2, const int* __restrict__ offs,
    float* __restrict__ m_arr, float* __restrict__ z_arr,
    float* __restrict__ Pp) {
  const int lane = threadIdx.x & 63;
  const int wid = threadIdx.x >> 6;
  const int wv = blockIdx.x * 4 + wid;   // global wave id
  const int wrow0 = wv << 4;             // first of my wave's 16 rows
  const int l15 = lane & 15;             // my row within the tile (A-frag m)
  const int l4 = lane >> 4;              // my k-chunk group

  // ---- part bookkeeping via ballot (no serial scans, no LDS) ----
  const int c = offs[lane + 1];          // lanes 0..63 -> offs[1..64]
  const unsigned long long mb = __ballot((c <= wrow0) && ((c & 15) != 0));
  const unsigned long long mi = __ballot((c > wrow0) && (c < wrow0 + WR));
  const int pbase = wv + __popcll(mb);
  const int npart = __popcll(mi) + 1;
  unsigned int bmap = 0;                 // bit r: part boundary before row r
  unsigned long long mm = mi;
  while (mm) {
    const int j = __ffsll((long long)mm) - 1;
    const int cr = __shfl(c, j) - wrow0;
    bmap |= 1u << cr;
    mm &= mm - 1;
  }
  const int pid = __popc(bmap & ((1u << (l15 + 1)) - 1u));  // my row's part id

  // ---- Phase 1: load my A-frag columns (row l15, cols 32ks+8*l4..+8), f32 ----
  const float* rp = feats + (size_t)(wrow0 + l15) * 512 + l4 * 8;
  float4 ra[16], rb[16];
  #pragma unroll
  for (int ks = 0; ks < 16; ++ks) {
    ra[ks] = *(const float4*)(rp + ks * 32);
    rb[ks] = *(const float4*)(rp + ks * 32 + 4);
  }
  // stats over my 128 cols, then reduce over the 4 lanes sharing row l15
  float s0 = 0.f, s1 = 0.f, q0 = 0.f, q1 = 0.f;
  #pragma unroll
  for (int ks = 0; ks < 16; ++ks) {
    s0 += (ra[ks].x + ra[ks].y) + (ra[ks].z + ra[ks].w);
    s1 += (rb[ks].x + rb[ks].y) + (rb[ks].z + rb[ks].w);
    q0 += ra[ks].x * ra[ks].x + ra[ks].y * ra[ks].y + ra[ks].z * ra[ks].z + ra[ks].w * ra[ks].w;
    q1 += rb[ks].x * rb[ks].x + rb[ks].y * rb[ks].y + rb[ks].z * rb[ks].z + rb[ks].w * rb[ks].w;
  }
  float sum = s0 + s1, sq = q0 + q1;
  sum += __shfl_xor(sum, 16); sum += __shfl_xor(sum, 32);
  sq  += __shfl_xor(sq, 16);  sq  += __shfl_xor(sq, 32);
  const float mean = sum * (1.0f / 512.0f);
  const float var  = sq * (1.0f / 512.0f) - mean * mean;
  const float rstd = rsqrtf(var + 1e-5f);

  // ---- Phase 2: normalize -> bf16 A-frags in registers (raw freed) ----
  uint4 af[16];
  #pragma unroll
  for (int ks = 0; ks < 16; ++ks) {
    const float* wp = ln_w + ks * 32 + l4 * 8;
    const float* bp = ln_b + ks * 32 + l4 * 8;
    const float4 w0 = *(const float4*)(wp);
    const float4 w1v = *(const float4*)(wp + 4);
    const float4 g0 = *(const float4*)(bp);
    const float4 g1 = *(const float4*)(bp + 4);
    const float x0 = (ra[ks].x - mean) * rstd * w0.x + g0.x;
    const float x1 = (ra[ks].y - mean) * rstd * w0.y + g0.y;
    const float x2 = (ra[ks].z - mean) * rstd * w0.z + g0.z;
    const float x3 = (ra[ks].w - mean) * rstd * w0.w + g0.w;
    const float y0 = (rb[ks].x - mean) * rstd * w1v.x + g1.x;
    const float y1 = (rb[ks].y - mean) * rstd * w1v.y + g1.y;
    const float y2 = (rb[ks].z - mean) * rstd * w1v.z + g1.z;
    const float y3 = (rb[ks].w - mean) * rstd * w1v.w + g1.w;
    af[ks].x = f2bf(x0) | (f2bf(x1) << 16);
    af[ks].y = f2bf(x2) | (f2bf(x3) << 16);
    af[ks].z = f2bf(y0) | (f2bf(y1) << 16);
    af[ks].w = f2bf(y2) | (f2bf(y3) << 16);
  }

  // ---- Phase 3: GEMM h[16x256] in two N-halves; epilogue folds GELU+w2 ----
  float sv0 = 0.f, sv1 = 0.f, sv2 = 0.f, sv3 = 0.f;
  #pragma unroll
  for (int nh = 0; nh < 2; ++nh) {
    f32x4 acc[8];
    #pragma unroll
    for (int nt = 0; nt < 8; ++nt) acc[nt] = f32x4{0.f, 0.f, 0.f, 0.f};
    #pragma unroll
    for (int ks = 0; ks < 16; ++ks) {
      const bf16x8 a = __builtin_bit_cast(bf16x8, af[ks]);
      #pragma unroll
      for (int nt = 0; nt < 8; ++nt) {
        const bf16x8 bv = *(const bf16x8*)(
            w1p + ((((ks * 4 + l4) << 8) + nh * 128 + nt * 16 + l15) << 3));
        acc[nt] = __builtin_amdgcn_mfma_f32_16x16x32_bf16(a, bv, acc[nt], 0, 0, 0);
      }
    }
    #pragma unroll
    for (int nt = 0; nt < 8; ++nt) {
      const int n = nh * 128 + nt * 16 + l15;
      const float b1v = b1[n], w2v = w2[n];
      sv0 += gelu_f(acc[nt][0] + b1v) * w2v;
      sv1 += gelu_f(acc[nt][1] + b1v) * w2v;
      sv2 += gelu_f(acc[nt][2] + b1v) * w2v;
      sv3 += gelu_f(acc[nt][3] + b1v) * w2v;
    }
  }
  // reduce over n (the 16 lanes of my l4 group); lane then holds s(4*l4+r)
  #pragma unroll
  for (int off = 1; off <= 8; off <<= 1) {
    sv0 += __shfl_xor(sv0, off);
    sv1 += __shfl_xor(sv1, off);
    sv2 += __shfl_xor(sv2, off);
    sv3 += __shfl_xor(sv3, off);
  }
  const float b2v = b2[0];
  // route s of row l15 to me: it lives in group l4 = l15>>2, register r = l15&3
  const int src = (l15 >> 2) << 4;
  const float t0 = __shfl(sv0, src), t1 = __shfl(sv1, src);
  const float t2 = __shfl(sv2, src), t3 = __shfl(sv3, src);
  const int rr = l15 & 3;
  const float s_mine = (rr == 0 ? t0 : (rr == 1 ? t1 : (rr == 2 ? t2 : t3))) + b2v;

  // ---- Phase 4: per-part m, z (masked butterflies over the 16 rows) ----
  float mym = s_mine;
  for (int k = 0; k < npart; ++k) {
    float mv = (pid == k) ? s_mine : -INFINITY;
    #pragma unroll
    for (int off = 1; off <= 8; off <<= 1) mv = fmaxf(mv, __shfl_xor(mv, off));
    if (pid == k) mym = mv;
    if (lane == 0) m_arr[pbase + k] = mv;
  }
  const float e_mine = __expf(s_mine - mym);
  for (int k = 0; k < npart; ++k) {
    float zv = (pid == k) ? e_mine : 0.0f;
    #pragma unroll
    for (int off = 1; off <= 8; off <<= 1) zv += __shfl_xor(zv, off);
    if (lane == 0) z_arr[pbase + k] = zv;
  }

  // ---- Phase 5: partial pool P[c] = sum_r e_r*feats[r][c]; tile is L2/L3-hot ----
  // lane owns cols [8*lane, 8*lane+8); e_r broadcast by one shuffle per row.
  const float* fp2 = feats + (size_t)wrow0 * 512 + lane * 8;
  float4 p0 = make_float4(0.f, 0.f, 0.f, 0.f);
  float4 p1 = make_float4(0.f, 0.f, 0.f, 0.f);
  int kp = 0;
  #pragma unroll
  for (int r = 0; r < WR; ++r) {
    if (bmap & (1u << r)) {   // wave-uniform, rare
      float* dst = Pp + (size_t)(pbase + kp) * 512 + lane * 8;
      *(float4*)dst = p0;
      *(float4*)(dst + 4) = p1;
      p0 = make_float4(0.f, 0.f, 0.f, 0.f);
      p1 = make_float4(0.f, 0.f, 0.f, 0.f);
      ++kp;
    }
    const float er = __shfl(e_mine, r);
    const float4 v0 = *(const float4*)(fp2 + (size_t)r * 512);
    const float4 v1 = *(const float4*)(fp2 + (size_t)r * 512 + 4);
    p0.x = fmaf(er, v0.x, p0.x); p0.y = fmaf(er, v0.y, p0.y);
    p0.z = fmaf(er, v0.z, p0.z); p0.w = fmaf(er, v0.w, p0.w);
    p1.x = fmaf(er, v1.x, p1.x); p1.y = fmaf(er, v1.y, p1.y);
    p1.z = fmaf(er, v1.z, p1.z); p1.w = fmaf(er, v1.w, p1.w);
  }
  float* dst = Pp + (size_t)(pbase + kp) * 512 + lane * 8;
  *(float4*)dst = p0;
  *(float4*)(dst + 4) = p1;
}

// ---------------- combine: two-level softmax merge; part ranges closed-form ----------------
__global__ __launch_bounds__(512) void combine_kernel(
    const int* __restrict__ offs, const float* __restrict__ m_arr,
    const float* __restrict__ z_arr, const float* __restrict__ Pp,
    float* __restrict__ out) {
  const int b = blockIdx.x;
  const int tid = threadIdx.x;
  const int lane = tid & 63, wid = tid >> 6;
  __shared__ int s_lohi[2];
  __shared__ float redM[8], redZ[8];

  if (wid == 0) {
    const int c = offs[lane + 1];
    const unsigned long long nal = __ballot((c & (WR - 1)) != 0);
    if (lane == 0) {
      const unsigned long long mlo = (b == 0) ? 0ull : ((1ull << b) - 1ull);
      const unsigned long long mhi = (b == 63) ? ~0ull : ((1ull << (b + 1)) - 1ull);
      s_lohi[0] = (offs[b] >> 4) + (int)__popcll(nal & mlo);
      s_lohi[1] = (offs[b + 1] >> 4) + (int)__popcll(nal & mhi) - 1;
    }
  }
  __syncthreads();
  const int lo = s_lohi[0], hi = s_lohi[1];

  float lm = -INFINITY;
  for (int p = lo + tid; p <= hi; p += 512) lm = fmaxf(lm, m_arr[p]);
  #pragma unroll
  for (int off = 32; off >= 1; off >>= 1) lm = fmaxf(lm, __shfl_xor(lm, off));
  if (lane == 0) redM[wid] = lm;
  __syncthreads();
  float M = redM[0];
  #pragma unroll
  for (int w = 1; w < 8; ++w) M = fmaxf(M, redM[w]);

  float lz = 0.0f;
  for (int p = lo + tid; p <= hi; p += 512) lz += z_arr[p] * __expf(m_arr[p] - M);
  #pragma unroll
  for (int off = 32; off >= 1; off >>= 1) lz += __shfl_xor(lz, off);
  if (lane == 0) redZ[wid] = lz;
  __syncthreads();
  float Z = 0.0f;
  #pragma unroll
  for (int w = 0; w < 8; ++w) Z += redZ[w];
  const float invZ = 1.0f / Z;

  float a0 = 0.f, a1 = 0.f, a2 = 0.f, a3 = 0.f;
  int p = lo;
  for (; p + 3 <= hi; p += 4) {
    a0 += __expf(m_arr[p] - M) * Pp[(size_t)p * 512 + tid];
    a1 += __expf(m_arr[p + 1] - M) * Pp[(size_t)(p + 1) * 512 + tid];
    a2 += __expf(m_arr[p + 2] - M) * Pp[(size_t)(p + 2) * 512 + tid];
    a3 += __expf(m_arr[p + 3] - M) * Pp[(size_t)(p + 3) * 512 + tid];
  }
  for (; p <= hi; ++p) a0 += __expf(m_arr[p] - M) * Pp[(size_t)p * 512 + tid];
  out[b * 512 + tid] = ((a0 + a1) + (a2 + a3)) * invZ;
}

extern "C" void kernel_launch(void* const* d_in, const int* in_sizes, int n_in,
                              void* d_out, int out_size, void* d_ws, size_t ws_size,
                              hipStream_t stream) {
  const float* feats = (const float*)d_in[0];
  const float* ln_w  = (const float*)d_in[1];
  const float* ln_b  = (const float*)d_in[2];
  const float* w1    = (const float*)d_in[3];
  const float* b1    = (const float*)d_in[4];
  const float* w2    = (const float*)d_in[5];
  const float* b2    = (const float*)d_in[6];
  const int* offs    = (const int*)d_in[7];
  float* out = (float*)d_out;

  char* ws = (char*)d_ws;
  unsigned short* w1p = (unsigned short*)(ws);            // 256 KB
  float* m_arr = (float*)(ws + (1 << 18));                // MAXPW f32 (~128 KB)
  float* z_arr = (float*)(ws + (1 << 19));                // MAXPW f32
  float* Pp    = (float*)(ws + (1 << 20));                // MAXPW*512 f32 (~67 MB)

  prep_w1<<<64, 256, 0, stream>>>(w1, w1p);
  fused_kernel<<<NWAVE / 4, 256, 0, stream>>>(feats, ln_w, ln_b, w1p, b1, w2, b2, offs,
                                              m_arr, z_arr, Pp);
  combine_kernel<<<NSEG, 512, 0, stream>>>(offs, m_arr, z_arr, Pp, out);
}

// Round 9
// 727.025 us; speedup vs baseline: 2.3107x; 2.3107x over previous
//
#include <hip/hip_runtime.h>

#define NPTS 524288
#define NSEG 64
#define RB 32                    // rows per block
#define NBLK (NPTS / RB)         // 16384 blocks
#define MAXP (NBLK + NSEG)       // max part records (16448)

typedef __bf16 bf16x8 __attribute__((ext_vector_type(8)));
typedef float f32x4 __attribute__((ext_vector_type(4)));

__device__ __forceinline__ unsigned int f2bf(float f) {
  unsigned int u = __float_as_uint(f);
  return (u + 0x7FFFu + ((u >> 16) & 1u)) >> 16;  // RNE bf16
}

// Branchless erf, Abramowitz-Stegun 7.1.26, |err| <= 1.5e-7
__device__ __forceinline__ float gelu_f(float h) {
  const float u = 0.70710678118654752f * h;
  const float a = fabsf(u);
  const float t = __builtin_amdgcn_rcpf(fmaf(0.3275911f, a, 1.0f));
  const float e = __expf(-a * a);
  float p = fmaf(1.061405429f, t, -1.453152027f);
  p = fmaf(p, t, 1.421413741f);
  p = fmaf(p, t, -0.284496736f);
  p = fmaf(p, t, 0.254829592f);
  p *= t;
  const float erfa = fmaf(-p, e, 1.0f);
  const float erfu = copysignf(erfa, u);
  return 0.5f * h * (1.0f + erfu);
}

// ---------------- prep: w1 [512][256] f32 -> bf16 packed [(k>>3)][n][k&7] ----------------
__global__ void prep_w1(const float* __restrict__ w1, unsigned short* __restrict__ w1p) {
  const int n = threadIdx.x;         // 0..255
  const int k0 = blockIdx.x * 8;     // 0..504
  unsigned int d[4];
  #pragma unroll
  for (int j = 0; j < 4; ++j) {
    const unsigned int lo = f2bf(w1[(size_t)(k0 + 2 * j) * 256 + n]);
    const unsigned int hi = f2bf(w1[(size_t)(k0 + 2 * j + 1) * 256 + n]);
    d[j] = lo | (hi << 16);
  }
  uint4* dst = (uint4*)(w1p + (size_t)blockIdx.x * 2048 + n * 8);
  *dst = make_uint4(d[0], d[1], d[2], d[3]);
}

// ---------------- fused: LN -> MFMA GEMM -> GELU -> s -> per-(block,seg) partial pool ----
// Block: 32 rows, 512 threads (8 waves), ~34KB LDS -> 3-4 blocks/CU (24-32 waves/CU).
// Single feats pass: partial pool re-reads the block's own 64KB tile (L2-hot).
__global__ __launch_bounds__(512, 6) void fused_kernel(
    const float* __restrict__ feats, const float* __restrict__ ln_w,
    const float* __restrict__ ln_b, const unsigned short* __restrict__ w1p,
    const float* __restrict__ b1, const float* __restrict__ w2,
    const float* __restrict__ b2, const int* __restrict__ offs,
    float* __restrict__ m_arr, float* __restrict__ z_arr,
    float* __restrict__ Pp) {
  __shared__ __align__(16) unsigned short xs[RB * 512];  // 32KB bf16 x-tile, XOR-swizzled
  __shared__ float sred[8][RB];
  __shared__ float e_all[RB];
  __shared__ int sh_bound[34];
  __shared__ int sh_meta[2];  // npart, pbase
  char* xsb = (char*)xs;
  const int tid = threadIdx.x;
  const int lane = tid & 63;
  const int wid = tid >> 6;
  const int r0 = blockIdx.x * RB;

  // ---- part bookkeeping: wave 0, ballot-based ----
  if (wid == 0) {
    const int c = offs[lane + 1];  // lanes 0..63 -> offs[1..64]
    const unsigned long long mb = __ballot((c <= r0) && ((c & (RB - 1)) != 0));
    const unsigned long long mi = __ballot((c > r0) && (c < r0 + RB));
    if ((c > r0) && (c < r0 + RB)) {
      const int rank = __popcll(mi & ((1ull << lane) - 1ull));
      sh_bound[rank + 1] = c - r0;
    }
    if (lane == 0) {
      const int npart = __popcll(mi) + 1;
      sh_bound[0] = 0;
      sh_bound[npart] = RB;
      sh_meta[0] = npart;
      sh_meta[1] = blockIdx.x + (int)__popcll(mb);
    }
  }

  // ---- Phase 1: LayerNorm, 4 rows per wave, hoisted loads, bf16 -> LDS ----
  const int c0 = lane * 4;
  const float4 lw0 = *(const float4*)(ln_w + c0);
  const float4 lw1 = *(const float4*)(ln_w + 256 + c0);
  const float4 lb0 = *(const float4*)(ln_b + c0);
  const float4 lb1 = *(const float4*)(ln_b + 256 + c0);

  float4 va[4], vb[4];
  {
    const float* bp = feats + (size_t)(r0 + wid * 4) * 512 + c0;
    #pragma unroll
    for (int rr = 0; rr < 4; ++rr) {
      va[rr] = *(const float4*)(bp + rr * 512);
      vb[rr] = *(const float4*)(bp + rr * 512 + 256);
    }
  }
  #pragma unroll
  for (int rr = 0; rr < 4; ++rr) {
    const int row = wid * 4 + rr;
    const float4 v0 = va[rr];
    const float4 v1 = vb[rr];
    float sum = (v0.x + v0.y) + (v0.z + v0.w) + (v1.x + v1.y) + (v1.z + v1.w);
    float sq  = v0.x * v0.x + v0.y * v0.y + v0.z * v0.z + v0.w * v0.w
              + v1.x * v1.x + v1.y * v1.y + v1.z * v1.z + v1.w * v1.w;
    #pragma unroll
    for (int off = 32; off >= 1; off >>= 1) {
      sum += __shfl_xor(sum, off);
      sq  += __shfl_xor(sq, off);
    }
    const float mean = sum * (1.0f / 512.0f);
    const float var  = sq * (1.0f / 512.0f) - mean * mean;
    const float rstd = rsqrtf(var + 1e-5f);
    const float x0 = (v0.x - mean) * rstd * lw0.x + lb0.x;
    const float x1 = (v0.y - mean) * rstd * lw0.y + lb0.y;
    const float x2 = (v0.z - mean) * rstd * lw0.z + lb0.z;
    const float x3 = (v0.w - mean) * rstd * lw0.w + lb0.w;
    const float y0 = (v1.x - mean) * rstd * lw1.x + lb1.x;
    const float y1 = (v1.y - mean) * rstd * lw1.y + lb1.y;
    const float y2 = (v1.z - mean) * rstd * lw1.z + lb1.z;
    const float y3 = (v1.w - mean) * rstd * lw1.w + lb1.w;
    const unsigned int p0 = f2bf(x0) | (f2bf(x1) << 16);
    const unsigned int p1 = f2bf(x2) | (f2bf(x3) << 16);
    const unsigned int p2 = f2bf(y0) | (f2bf(y1) << 16);
    const unsigned int p3 = f2bf(y2) | (f2bf(y3) << 16);
    const unsigned int a0 = ((unsigned int)(row * 1024 + c0 * 2)) ^ (((unsigned int)(row & 7)) << 4);
    const unsigned int a1 = ((unsigned int)(row * 1024 + 512 + c0 * 2)) ^ (((unsigned int)(row & 7)) << 4);
    *(uint2*)(xsb + a0) = make_uint2(p0, p1);
    *(uint2*)(xsb + a1) = make_uint2(p2, p3);
  }
  __syncthreads();

  // ---- Phase 2: GEMM  h[32x256] = x[32x512] @ w1; wave owns 32 N-cols, mt=2 ----
  const int l15 = lane & 15, l4 = lane >> 4;
  const int nb = wid * 32;
  f32x4 acc[2][2];
  #pragma unroll
  for (int i = 0; i < 2; ++i)
    #pragma unroll
    for (int j = 0; j < 2; ++j)
      acc[i][j] = f32x4{0.f, 0.f, 0.f, 0.f};

  #pragma unroll 4
  for (int ks = 0; ks < 16; ++ks) {
    bf16x8 av[2], bv[2];
    #pragma unroll
    for (int mt = 0; mt < 2; ++mt) {
      const int row = mt * 16 + l15;
      const unsigned int ad =
          ((unsigned int)(row * 1024 + ks * 64 + l4 * 16)) ^ (((unsigned int)(row & 7)) << 4);
      av[mt] = *(const bf16x8*)(xsb + ad);
    }
    #pragma unroll
    for (int nt = 0; nt < 2; ++nt) {
      const int idx = (((ks * 4 + l4) << 8) + nb + nt * 16 + l15) << 3;
      bv[nt] = *(const bf16x8*)(w1p + idx);
    }
    #pragma unroll
    for (int mt = 0; mt < 2; ++mt)
      #pragma unroll
      for (int nt = 0; nt < 2; ++nt)
        acc[mt][nt] = __builtin_amdgcn_mfma_f32_16x16x32_bf16(av[mt], bv[nt], acc[mt][nt], 0, 0, 0);
  }

  // ---- Epilogue: s_row = sum_n gelu(acc + b1) * w2 ----
  float b1v[2], w2v[2];
  #pragma unroll
  for (int nt = 0; nt < 2; ++nt) {
    const int n = nb + nt * 16 + l15;
    b1v[nt] = b1[n];
    w2v[nt] = w2[n];
  }
  #pragma unroll
  for (int mt = 0; mt < 2; ++mt) {
    #pragma unroll
    for (int r = 0; r < 4; ++r) {
      float v = 0.0f;
      #pragma unroll
      for (int nt = 0; nt < 2; ++nt) {
        const float h = acc[mt][nt][r] + b1v[nt];
        v += gelu_f(h) * w2v[nt];
      }
      v += __shfl_xor(v, 1);
      v += __shfl_xor(v, 2);
      v += __shfl_xor(v, 4);
      v += __shfl_xor(v, 8);
      if (l15 == 0) sred[wid][mt * 16 + l4 * 4 + r] = v;
    }
  }
  __syncthreads();

  // ---- Phase 3 (wave 0): per-part m, z, e[row]; lanes >= RB masked ----
  if (wid == 0) {
    const int npart = sh_meta[0], pbase = sh_meta[1];
    const bool valid = lane < RB;
    float sv;
    if (valid) {
      sv = b2[0];
      #pragma unroll
      for (int w = 0; w < 8; ++w) sv += sred[w][lane];
    } else {
      sv = -INFINITY;
    }
    int pid = 0;
    for (int i = 1; i < npart; ++i) pid += (sh_bound[i] <= lane) ? 1 : 0;
    if (!valid) pid = npart - 1;
    float mym = -INFINITY;
    for (int k = 0; k < npart; ++k) {
      float mv = (pid == k) ? sv : -INFINITY;
      #pragma unroll
      for (int off = 32; off >= 1; off >>= 1) mv = fmaxf(mv, __shfl_xor(mv, off));
      if (pid == k) mym = mv;
      if (lane == 0) m_arr[pbase + k] = mv;
    }
    const float e = __expf(sv - mym);  // lanes >= RB: exp(-inf - m) = 0
    if (valid) e_all[lane] = e;
    for (int k = 0; k < npart; ++k) {
      float zv = (pid == k) ? e : 0.0f;
      #pragma unroll
      for (int off = 32; off >= 1; off >>= 1) zv += __shfl_xor(zv, off);
      if (lane == 0) z_arr[pbase + k] = zv;
    }
  }
  __syncthreads();

  // ---- Phase 4: partial pool P[c] = sum_rows e[r]*feats[r][c] (block tile L2-hot) ----
  // 512 threads: thread owns f32 column `tid`; 4 independent FMA chains.
  {
    const int pbase = sh_meta[1];
    const float* fp = feats + (size_t)r0 * 512;
    float a0 = 0.f, a1 = 0.f, a2 = 0.f, a3 = 0.f;
    int k = 0;
    #pragma unroll 4
    for (int r = 0; r < RB; ++r) {
      if (r == sh_bound[k + 1]) {        // wave-uniform, rare
        Pp[(size_t)(pbase + k) * 512 + tid] = (a0 + a1) + (a2 + a3);
        a0 = a1 = a2 = a3 = 0.f;
        ++k;
      }
      const float v = e_all[r] * fp[(size_t)r * 512 + tid];
      if ((r & 3) == 0) a0 += v;
      else if ((r & 3) == 1) a1 += v;
      else if ((r & 3) == 2) a2 += v;
      else a3 += v;
    }
    Pp[(size_t)(pbase + k) * 512 + tid] = (a0 + a1) + (a2 + a3);
  }
}

// ---------------- combine: two-level softmax merge; part ranges closed-form ----------------
__global__ __launch_bounds__(512) void combine_kernel(
    const int* __restrict__ offs, const float* __restrict__ m_arr,
    const float* __restrict__ z_arr, const float* __restrict__ Pp,
    float* __restrict__ out) {
  const int b = blockIdx.x;
  const int tid = threadIdx.x;
  const int lane = tid & 63, wid = tid >> 6;
  __shared__ int s_lohi[2];
  __shared__ float redM[8], redZ[8];

  if (wid == 0) {
    const int c = offs[lane + 1];
    const unsigned long long nal = __ballot((c & (RB - 1)) != 0);
    if (lane == 0) {
      const unsigned long long mlo = (b == 0) ? 0ull : ((1ull << b) - 1ull);
      const unsigned long long mhi = (b == 63) ? ~0ull : ((1ull << (b + 1)) - 1ull);
      s_lohi[0] = (offs[b] >> 5) + (int)__popcll(nal & mlo);
      s_lohi[1] = (offs[b + 1] >> 5) + (int)__popcll(nal & mhi) - 1;
    }
  }
  __syncthreads();
  const int lo = s_lohi[0], hi = s_lohi[1];

  float lm = -INFINITY;
  for (int p = lo + tid; p <= hi; p += 512) lm = fmaxf(lm, m_arr[p]);
  #pragma unroll
  for (int off = 32; off >= 1; off >>= 1) lm = fmaxf(lm, __shfl_xor(lm, off));
  if (lane == 0) redM[wid] = lm;
  __syncthreads();
  float M = redM[0];
  #pragma unroll
  for (int w = 1; w < 8; ++w) M = fmaxf(M, redM[w]);

  float lz = 0.0f;
  for (int p = lo + tid; p <= hi; p += 512) lz += z_arr[p] * __expf(m_arr[p] - M);
  #pragma unroll
  for (int off = 32; off >= 1; off >>= 1) lz += __shfl_xor(lz, off);
  if (lane == 0) redZ[wid] = lz;
  __syncthreads();
  float Z = 0.0f;
  #pragma unroll
  for (int w = 0; w < 8; ++w) Z += redZ[w];
  const float invZ = 1.0f / Z;

  float a0 = 0.f, a1 = 0.f, a2 = 0.f, a3 = 0.f;
  int p = lo;
  for (; p + 3 <= hi; p += 4) {
    a0 += __expf(m_arr[p] - M) * Pp[(size_t)p * 512 + tid];
    a1 += __expf(m_arr[p + 1] - M) * Pp[(size_t)(p + 1) * 512 + tid];
    a2 += __expf(m_arr[p + 2] - M) * Pp[(size_t)(p + 2) * 512 + tid];
    a3 += __expf(m_arr[p + 3] - M) * Pp[(size_t)(p + 3) * 512 + tid];
  }
  for (; p <= hi; ++p) a0 += __expf(m_arr[p] - M) * Pp[(size_t)p * 512 + tid];
  out[b * 512 + tid] = ((a0 + a1) + (a2 + a3)) * invZ;
}

extern "C" void kernel_launch(void* const* d_in, const int* in_sizes, int n_in,
                              void* d_out, int out_size, void* d_ws, size_t ws_size,
                              hipStream_t stream) {
  const float* feats = (const float*)d_in[0];
  const float* ln_w  = (const float*)d_in[1];
  const float* ln_b  = (const float*)d_in[2];
  const float* w1    = (const float*)d_in[3];
  const float* b1    = (const float*)d_in[4];
  const float* w2    = (const float*)d_in[5];
  const float* b2    = (const float*)d_in[6];
  const int* offs    = (const int*)d_in[7];
  float* out = (float*)d_out;

  char* ws = (char*)d_ws;
  unsigned short* w1p = (unsigned short*)(ws);            // 256 KB
  float* m_arr = (float*)(ws + (1 << 18));                // MAXP f32 (~66 KB)
  float* z_arr = (float*)(ws + (1 << 19));                // MAXP f32
  float* Pp    = (float*)(ws + (1 << 20));                // MAXP*512 f32 (~33.7 MB)

  prep_w1<<<64, 256, 0, stream>>>(w1, w1p);
  fused_kernel<<<NBLK, 512, 0, stream>>>(feats, ln_w, ln_b, w1p, b1, w2, b2, offs,
                                         m_arr, z_arr, Pp);
  combine_kernel<<<NSEG, 512, 0, stream>>>(offs, m_arr, z_arr, Pp, out);
}